// Round 5
// baseline (27.400 us; speedup 1.0000x reference)
//
#include <hip/hip_runtime.h>
#include <math.h>

// forecast (32,20,96,96) f32, truth (32,96,96) f32 -> scalar f32
#define M_ENS 20
#define HW    9216            // 96*96 pixels per image
#define BHWf  294912.0f
#define BLOCK 256
#define BPI   36              // blocks per image: 36*256 == 9216 exact

__global__ void __launch_bounds__(BLOCK)
crps_atomic_kernel(const float* __restrict__ forecast,
                   const float* __restrict__ truth,
                   float* __restrict__ out) {
    int b  = blockIdx.y;                             // image index 0..31
    int hw = blockIdx.x * BLOCK + threadIdx.x;       // pixel in image, exact cover
    const float* fp = forecast + (size_t)b * (M_ENS * HW) + hw;

    float x[M_ENS];
    #pragma unroll
    for (int e = 0; e < M_ENS; ++e) x[e] = fp[e * HW];
    float y = truth[b * HW + hw];

    float dxy = 0.0f, sum = 0.0f;
    #pragma unroll
    for (int e = 0; e < M_ENS; ++e) {
        dxy += fabsf(x[e] - y);
        sum += x[e];
    }

    float tri = 0.0f;                                // upper-triangle pair sum
    #pragma unroll
    for (int i = 0; i < M_ENS; ++i) {
        #pragma unroll
        for (int j = i + 1; j < M_ENS; ++j) {
            tri += fabsf(x[i] - x[j]);
        }
    }

    float mean = sum * (1.0f / M_ENS);
    float var = 0.0f;
    #pragma unroll
    for (int e = 0; e < M_ENS; ++e) {
        float d = x[e] - mean;
        var += d * d;
    }
    float stdv = sqrtf(var * (1.0f / (M_ENS - 1)));  // ddof=1
    float ks = 3.3f * stdv;

    float pen = 0.0f;
    #pragma unroll
    for (int e = 0; e < M_ENS; ++e) {
        float dev = fabsf(x[e] - mean);
        float p = dev - ks;
        pen += (p > 0.0f) ? p : 0.0f;
    }

    // crps_px = dxy/m - tri/m^2 (diag zero); fold final coefficients now
    float s = (dxy * (1.0f / M_ENS) - tri * (1.0f / (M_ENS * M_ENS))) * (1.0f / BHWf)
            + pen * (0.02f / (BHWf * M_ENS));

    // wave64 shuffle reduce, then 4-entry LDS cross-wave reduce
    #pragma unroll
    for (int off = 32; off > 0; off >>= 1)
        s += __shfl_down(s, off, 64);

    __shared__ float sw[BLOCK / 64];
    int wave = threadIdx.x >> 6;
    int lane = threadIdx.x & 63;
    if (lane == 0) sw[wave] = s;
    __syncthreads();
    if (threadIdx.x == 0) {
        float t = sw[0] + sw[1] + sw[2] + sw[3];
        atomicAdd(out, t);                           // device-scope, cross-XCD safe
    }
}

extern "C" void kernel_launch(void* const* d_in, const int* in_sizes, int n_in,
                              void* d_out, int out_size, void* d_ws, size_t ws_size,
                              hipStream_t stream) {
    const float* forecast = (const float*)d_in[0];
    const float* truth    = (const float*)d_in[1];
    float* out = (float*)d_out;

    hipMemsetAsync(out, 0, sizeof(float), stream);   // out[0] = 0.0f each call
    dim3 grid(BPI, 32);
    crps_atomic_kernel<<<grid, BLOCK, 0, stream>>>(forecast, truth, out);
}